// Round 3
// baseline (379.202 us; speedup 1.0000x reference)
//
#include <hip/hip_runtime.h>
#include <stdint.h>

// ============================================================================
// AttentionBlock: out = concat([x, softmax(QK^T/32) @ V], -1)
//   B=4, S=2048, D=1024, fp32 in/out.
//
// fp32 emulated via f16 hi/lo split on the Q/K/logits path, folded into the
// K dimension: A''=[Ah|Al|Ah], B''=[Bh|Bh|Bl], K=3072 -> plain f16 GEMMs
// with a per-K-region source table.
//
// ONE 8-phase 256x256 template (BK=64, 8 waves, 128KiB LDS, dbuf). Per phase:
//   {12x ds_read_b128 (XOR-swizzled) -> stage one quadrant-unit of tile kt+1
//    via global_load_lds(16B, pre-swizzled source) -> s_barrier -> lgkmcnt(0)
//    -> sched_barrier -> setprio(1) 16x MFMA setprio(0) -> [counted vmcnt]
//    -> s_barrier}.
// RACE FIX vs prev round: counted vmcnt sits BEFORE the end-of-phase barrier
// (publish = own-wave vmcnt + all-wave barrier), not at phase entry where it
// only proved this wave's loads had landed. Deadline math: units staged in
// order Aq0,Bq0,Bq1,Aq1 (2 loads each); trailing waits per tile = 4,4,-,4;
// last tile peeled with 2,0,-,-. Never 0 in the main loop (T4).
//
// ws layout (144 MiB):
//    0 MB Qh | 16 Ql | 32 Kh | 48 Kl | 64 VT f16 [4][1024][2048]
//   80 MB S f32 [4][2048][2048] (P f16 written in-place, row stride 8192B)
//   overlay on S (dead before S written): 80 xh | 96 xl | 112.. W*T hi/lo
// ============================================================================

typedef _Float16 h8 __attribute__((ext_vector_type(8)));
typedef _Float16 h4 __attribute__((ext_vector_type(4)));
typedef float    f4 __attribute__((ext_vector_type(4)));

#define VMCNT(n) asm volatile("s_waitcnt vmcnt(" #n ")" ::: "memory")
#define BAR() __builtin_amdgcn_s_barrier()

__device__ __forceinline__ void gl_lds16(const _Float16* g, _Float16* l) {
  __builtin_amdgcn_global_load_lds(
      (const __attribute__((address_space(1))) unsigned int*)g,
      (__attribute__((address_space(3))) unsigned int*)l, 16, 0, 0);
}

// ---------------------------------------------------------------- prep ----
__global__ __launch_bounds__(256) void prep_x_split_copy(
    const float* __restrict__ x, _Float16* __restrict__ xh,
    _Float16* __restrict__ xl, float* __restrict__ out) {
  size_t i = (size_t)blockIdx.x * 256 + threadIdx.x;  // one f4 per thread
  f4 v = ((const f4*)x)[i];
  h4 hi, lo;
#pragma unroll
  for (int j = 0; j < 4; ++j) {
    _Float16 h = (_Float16)v[j];
    hi[j] = h;
    lo[j] = (_Float16)(v[j] - (float)h);
  }
  ((h4*)xh)[i] = hi;
  ((h4*)xl)[i] = lo;
  size_t r = i >> 8, c = i & 255;       // out[:, :1024] = x (fused copy)
  ((f4*)out)[r * 512 + c] = v;
}

__global__ __launch_bounds__(256) void prep_w_split(const float* __restrict__ W,
                                                    _Float16* __restrict__ WTh,
                                                    _Float16* __restrict__ WTl) {
  int i = blockIdx.x * 256 + threadIdx.x;
  int d = i >> 10, e = i & 1023;
  float v = W[i];
  _Float16 h = (_Float16)v;
  WTh[e * 1024 + d] = h;
  if (WTl) WTl[e * 1024 + d] = (_Float16)(v - (float)h);
}

// ---------------------------------------------------------------- gemm ----
enum { EM_F32 = 0, EM_QK = 1, EM_VT = 2 };

struct G8 {
  const _Float16* Areg[3]; long zA; int lda;     // A region table (k0>>10)
  const _Float16* Breg[4][3]; long zB; int ldb;  // B region table per z
  int NT[4];     // K-tiles (K/64) per z
  int emode[4];  // epilogue per z
  float* Cf; long zC; int ldc; float scale;      // EM_F32
  _Float16* Ch[4]; _Float16* Cl[4];              // EM_QK (ld = 1024)
  _Float16* Vt;                                  // EM_VT: [b][1024][2048]
};

__global__ __launch_bounds__(512) void gemm8p(G8 p) {
  __shared__ alignas(16) _Float16 lds[2][2][256][64];  // [buf][A/B][row][col]
  const int t = threadIdx.x;
  const int lane = t & 63;
  const int w = t >> 6;
  const int wm = w >> 2, wn = w & 3;           // wave grid 2(M) x 4(N)
  const int l15 = lane & 15, l4 = lane >> 4;
  const int z = blockIdx.z;
  const long Mb = (long)blockIdx.y * 256;
  const long Nb = (long)blockIdx.x * 256;
  const int nt = p.NT[z];
  const long zAo = p.zA * z;
  const long zBo = p.zB * z;
  const int lda = p.lda, ldb = p.ldb;

  const int rr_lo = t >> 3;            // staging: 8 lanes per 64-f16 row
  const int slot = t & 7;
  const int rr0_lo = (t & ~63) >> 3;   // wave-uniform row part

  f4 acc[8][4] = {};                   // wave tile 128x64: frag[i<8][j<4]

  // stage unit u (0:A qm=0, 1:B qn=0, 2:B qn=1, 3:A qm=1) of tile kt -> buf sb
  auto stage = [&](int u, int sb, int kt) {
    const int k0 = kt << 6;
    const int r = k0 >> 10;
    const int cn = k0 & 1023;
    const _Float16* Ab = p.Areg[r] + zAo + cn;
    const _Float16* Bb = p.Breg[z][r] + zBo + cn;
#pragma unroll
    for (int i = 0; i < 2; ++i) {
      int rr = i * 64 + rr_lo;
      int rr0 = i * 64 + rr0_lo;
      if (u == 0 || u == 3) {
        int qm = (u == 3);
        int row  = ((rr  >> 6) << 7) | (qm << 6) | (rr  & 63);
        int row0 = ((rr0 >> 6) << 7) | (qm << 6) | (rr0 & 63);
        int scol = (slot ^ (row & 7)) << 3;     // pre-swizzled source (T2)
        gl_lds16(Ab + (Mb + row) * (long)lda + scol, &lds[sb][0][row0][0]);
      } else {
        int qn = (u == 2);
        int row  = ((rr  >> 5) << 6) | (qn << 5) | (rr  & 31);
        int row0 = ((rr0 >> 5) << 6) | (qn << 5) | (rr0 & 31);
        int scol = (slot ^ (row & 7)) << 3;
        gl_lds16(Bb + (Nb + row) * (long)ldb + scol, &lds[sb][1][row0][0]);
      }
    }
  };

  // phase body: dsread(current) ; stage unit q of kt+1 ; mid-bar ; MFMA.
  // NO trailing sync here — caller appends [counted vmcnt] + end barrier.
  auto phase = [&](int q, int kt, bool dostage) {
    const int buf = kt & 1;
    const int qm = q >> 1, qn = q & 1;
    h8 af[4][2];
    h8 bf[2][2];
#pragma unroll
    for (int m = 0; m < 4; ++m) {
      int row = wm * 128 + (qm * 4 + m) * 16 + l15;
#pragma unroll
      for (int ks = 0; ks < 2; ++ks)
        af[m][ks] = *(const h8*)&lds[buf][0][row][(((ks * 4 + l4) ^ (row & 7)) << 3)];
    }
#pragma unroll
    for (int n = 0; n < 2; ++n) {
      int row = wn * 64 + (qn * 2 + n) * 16 + l15;
#pragma unroll
      for (int ks = 0; ks < 2; ++ks)
        bf[n][ks] = *(const h8*)&lds[buf][1][row][(((ks * 4 + l4) ^ (row & 7)) << 3)];
    }
    if (dostage) stage(q, buf ^ 1, kt + 1);
    __builtin_amdgcn_s_barrier();
    asm volatile("s_waitcnt lgkmcnt(0)" ::: "memory");
    __builtin_amdgcn_sched_barrier(0);
    __builtin_amdgcn_s_setprio(1);
#pragma unroll
    for (int ks = 0; ks < 2; ++ks)
#pragma unroll
      for (int m = 0; m < 4; ++m)
#pragma unroll
        for (int n = 0; n < 2; ++n)
          acc[qm * 4 + m][qn * 2 + n] = __builtin_amdgcn_mfma_f32_16x16x32_f16(
              af[m][ks], bf[n][ks], acc[qm * 4 + m][qn * 2 + n], 0, 0, 0);
    __builtin_amdgcn_s_setprio(0);
  };

  // prologue: stage tile 0 (deadline order), publish u0+u1
  stage(0, 0, 0); stage(1, 0, 0); stage(2, 0, 0); stage(3, 0, 0);
  VMCNT(4);
  BAR();

  for (int kt = 0; kt < nt - 1; ++kt) {
    phase(0, kt, true);  VMCNT(4); BAR();   // publishes Bq1(kt)
    phase(1, kt, true);  VMCNT(4); BAR();   // publishes Aq1(kt)
    phase(2, kt, true);            BAR();
    phase(3, kt, true);  VMCNT(4); BAR();   // publishes Aq0,Bq0(kt+1)
  }
  {  // last tile: no staging, peeled counted waits
    int kt = nt - 1;
    phase(0, kt, false); VMCNT(2); BAR();   // publishes Bq1
    phase(1, kt, false); VMCNT(0); BAR();   // publishes Aq1
    phase(2, kt, false);           BAR();
    phase(3, kt, false);                    // epilogue is LDS-free
  }

  // epilogue: C/D map col=lane&15, row=(lane>>4)*4+reg (m89/m91, round-1 OK)
  const int em = p.emode[z];
  const long gr0 = wm * 128 + l4 * 4;
  const long gc0 = wn * 64 + l15;
  if (em == EM_F32) {
    float* C = p.Cf + p.zC * z;
#pragma unroll
    for (int i = 0; i < 8; ++i)
#pragma unroll
      for (int j = 0; j < 4; ++j) {
        long gr = Mb + gr0 + i * 16;
        long gc = Nb + gc0 + j * 16;
#pragma unroll
        for (int r = 0; r < 4; ++r)
          C[(gr + r) * (long)p.ldc + gc] = acc[i][j][r] * p.scale;
      }
  } else if (em == EM_QK) {
    _Float16* Ch = p.Ch[z];
    _Float16* Cl = p.Cl[z];
#pragma unroll
    for (int i = 0; i < 8; ++i)
#pragma unroll
      for (int j = 0; j < 4; ++j) {
        long gr = Mb + gr0 + i * 16;
        long gc = Nb + gc0 + j * 16;
#pragma unroll
        for (int r = 0; r < 4; ++r) {
          float c = acc[i][j][r];
          _Float16 h = (_Float16)c;
          Ch[(gr + r) * 1024 + gc] = h;
          Cl[(gr + r) * 1024 + gc] = (_Float16)(c - (float)h);
        }
      }
  } else {  // EM_VT: rows = b*2048+s, col = d -> Vt[b][d][s], 4 contiguous s
    _Float16* Vt = p.Vt;
#pragma unroll
    for (int i = 0; i < 8; ++i)
#pragma unroll
      for (int j = 0; j < 4; ++j) {
        long gr = Mb + gr0 + i * 16;
        long gc = Nb + gc0 + j * 16;
        long b = gr >> 11, s = gr & 2047;
        h4 hv;
#pragma unroll
        for (int r = 0; r < 4; ++r) hv[r] = (_Float16)acc[i][j][r];
        *(h4*)&Vt[b * (long)(1024 * 2048) + gc * 2048 + s] = hv;
      }
  }
}

// ------------------------------------------------------------- softmax ----
__global__ __launch_bounds__(256) void softmax_rows(float* __restrict__ Sb) {
  const int t = threadIdx.x;
  float* row = Sb + (size_t)blockIdx.x * 2048;
  f4 v0 = ((const f4*)row)[t];
  f4 v1 = ((const f4*)row)[t + 256];
  float mx = -3.0e38f;
#pragma unroll
  for (int j = 0; j < 4; ++j) { mx = fmaxf(mx, v0[j]); mx = fmaxf(mx, v1[j]); }
#pragma unroll
  for (int o = 32; o > 0; o >>= 1) mx = fmaxf(mx, __shfl_xor(mx, o));
  __shared__ float red[4], red2[4];
  const int wave = t >> 6, lane = t & 63;
  if (lane == 0) red[wave] = mx;
  __syncthreads();
  mx = fmaxf(fmaxf(red[0], red[1]), fmaxf(red[2], red[3]));
  float pv[8];
  float sum = 0.f;
#pragma unroll
  for (int j = 0; j < 4; ++j) { pv[j] = __expf(v0[j] - mx); pv[4 + j] = __expf(v1[j] - mx); }
#pragma unroll
  for (int j = 0; j < 8; ++j) sum += pv[j];
#pragma unroll
  for (int o = 32; o > 0; o >>= 1) sum += __shfl_xor(sum, o);
  if (lane == 0) red2[wave] = sum;
  __syncthreads();  // orders all row reads before in-place f16 writes
  sum = red2[0] + red2[1] + red2[2] + red2[3];
  float inv = 1.0f / sum;
  h4 o0, o1;
#pragma unroll
  for (int j = 0; j < 4; ++j) { o0[j] = (_Float16)(pv[j] * inv); o1[j] = (_Float16)(pv[4 + j] * inv); }
  _Float16* prow = (_Float16*)row;
  ((h4*)prow)[t] = o0;
  ((h4*)prow)[t + 256] = o1;
}

// ---------------------------------------------------------------- misc ----
__global__ __launch_bounds__(256) void copy_x_half(const float* __restrict__ x,
                                                   float* __restrict__ out) {
  size_t i = (size_t)blockIdx.x * 256 + threadIdx.x;
  size_t r = i >> 8, c = i & 255;
  ((f4*)out)[r * 512 + c] = ((const f4*)x)[i];
}

__global__ void ws_sentinel(float* out, float v) { out[0] = v; }

// -------------------------------------------------------------- launch ----
extern "C" void kernel_launch(void* const* d_in, const int* in_sizes, int n_in,
                              void* d_out, int out_size, void* d_ws, size_t ws_size,
                              hipStream_t stream) {
  const float* x  = (const float*)d_in[0];
  const float* Wq = (const float*)d_in[1];
  const float* Wk = (const float*)d_in[2];
  const float* Wv = (const float*)d_in[3];
  float* out = (float*)d_out;

  const size_t MB = 1ull << 20;
  char* w = (char*)d_ws;
  _Float16* Qh = (_Float16*)(w + 0 * MB);
  _Float16* Ql = (_Float16*)(w + 16 * MB);
  _Float16* Kh = (_Float16*)(w + 32 * MB);
  _Float16* Kl = (_Float16*)(w + 48 * MB);
  _Float16* VT = (_Float16*)(w + 64 * MB);
  float*    S  = (float*)   (w + 80 * MB);
  _Float16* xh = (_Float16*)(w + 80 * MB);  // overlays S (dead before S write)
  _Float16* xl = (_Float16*)(w + 96 * MB);
  _Float16* WqhT = (_Float16*)(w + 112 * MB);
  _Float16* WqlT = (_Float16*)(w + 114 * MB);
  _Float16* WkhT = (_Float16*)(w + 116 * MB);
  _Float16* WklT = (_Float16*)(w + 118 * MB);
  _Float16* WvhT = (_Float16*)(w + 120 * MB);

  if (ws_size < 144 * MB) {  // fail loud: absmax reports ~ws_size
    copy_x_half<<<8192, 256, 0, stream>>>(x, out);
    ws_sentinel<<<1, 1, 0, stream>>>(out, (float)ws_size);
    return;
  }

  prep_x_split_copy<<<8192, 256, 0, stream>>>(x, xh, xl, out);
  prep_w_split<<<4096, 256, 0, stream>>>(Wq, WqhT, WqlT);
  prep_w_split<<<4096, 256, 0, stream>>>(Wk, WkhT, WklT);
  prep_w_split<<<4096, 256, 0, stream>>>(Wv, WvhT, (_Float16*)nullptr);

  // --- Q,K (split, K=3072) + V (plain, K=1024) in one 384-block launch ---
  G8 pp = {};
  pp.Areg[0] = xh; pp.Areg[1] = xl; pp.Areg[2] = xh; pp.zA = 0; pp.lda = 1024;
  pp.Breg[0][0] = WqhT; pp.Breg[0][1] = WqhT; pp.Breg[0][2] = WqlT;
  pp.Breg[1][0] = WkhT; pp.Breg[1][1] = WkhT; pp.Breg[1][2] = WklT;
  pp.Breg[2][0] = WvhT; pp.Breg[2][1] = WvhT; pp.Breg[2][2] = WvhT;
  pp.zB = 0; pp.ldb = 1024;
  pp.NT[0] = 48; pp.NT[1] = 48; pp.NT[2] = 16;
  pp.emode[0] = EM_QK; pp.emode[1] = EM_QK; pp.emode[2] = EM_VT;
  pp.Ch[0] = Qh; pp.Cl[0] = Ql; pp.Ch[1] = Kh; pp.Cl[1] = Kl;
  pp.Vt = VT;
  gemm8p<<<dim3(4, 32, 3), 512, 0, stream>>>(pp);

  // --- S = (Q K^T)/32, split K=3072, 256 blocks ---
  G8 ps = {};
  ps.Areg[0] = Qh; ps.Areg[1] = Ql; ps.Areg[2] = Qh;
  ps.zA = 2048L * 1024; ps.lda = 1024;
  for (int zz = 0; zz < 4; ++zz) {
    ps.Breg[zz][0] = Kh; ps.Breg[zz][1] = Kh; ps.Breg[zz][2] = Kl;
    ps.NT[zz] = 48; ps.emode[zz] = EM_F32;
  }
  ps.zB = 2048L * 1024; ps.ldb = 1024;
  ps.Cf = S; ps.zC = 2048L * 2048; ps.ldc = 2048; ps.scale = 0.03125f;
  gemm8p<<<dim3(8, 8, 4), 512, 0, stream>>>(ps);

  softmax_rows<<<8192, 256, 0, stream>>>(S);

  // --- attn = P @ V -> out[:, :, 1024:], plain K=2048, 128 blocks ---
  G8 po = {};
  const _Float16* P = (const _Float16*)S;  // rows stride 4096 f16
  po.Areg[0] = P; po.Areg[1] = P + 1024; po.Areg[2] = P;
  po.zA = 2048L * 4096; po.lda = 4096;
  for (int zz = 0; zz < 4; ++zz) {
    po.Breg[zz][0] = VT; po.Breg[zz][1] = VT + 1024; po.Breg[zz][2] = VT;
    po.NT[zz] = 32; po.emode[zz] = EM_F32;
  }
  po.zB = 1024L * 2048; po.ldb = 2048;
  po.Cf = out + 1024; po.zC = 2048L * 2048; po.ldc = 2048; po.scale = 1.f;
  gemm8p<<<dim3(4, 8, 4), 512, 0, stream>>>(po);
}